// Round 5
// baseline (332.652 us; speedup 1.0000x reference)
//
#include <hip/hip_runtime.h>
#include <math.h>

static constexpr int B_ = 8, C_ = 512, T_ = 2048, C3_ = 1536;
static constexpr float INV_TEMP = 1.0f / 0.07f;

typedef __attribute__((ext_vector_type(8))) short short8;
typedef __attribute__((ext_vector_type(4))) float floatx4;

__device__ __forceinline__ float b2f(unsigned short u) {
  union { unsigned int i; float f; } v; v.i = ((unsigned int)u) << 16; return v.f;
}
__device__ __forceinline__ unsigned short f2b(float f) {
  union { float f; unsigned int i; } v; v.f = f;
  const unsigned int x = v.i;
  return (unsigned short)((x + 0x7FFFu + ((x >> 16) & 1u)) >> 16);
}
__device__ __forceinline__ void gld16(const unsigned short* g, unsigned short* l) {
  __builtin_amdgcn_global_load_lds(
      (const __attribute__((address_space(1))) void*)g,
      (__attribute__((address_space(3))) void*)l, 16, 0, 0);
}

// ---------------------------------------------------------------------------
// gemm_tn: proven 128x128/BK=32 TN bf16 GEMM (3-deep LDS ring, counted
// vmcnt(4) at the barrier). Used for qkv / AV / proj.
// MODE 0: plain store. MODE 2: softmax epilogue. MODE 3: row divide.
// ---------------------------------------------------------------------------
template<bool OUT_BF16, int MODE>
__global__ __launch_bounds__(256)
void gemm_tn(const unsigned short* __restrict__ A, const unsigned short* __restrict__ B,
             void* __restrict__ Cout, int K, int lda, int ldb, int ldc,
             long long sA, long long sB, long long sC,
             const float* __restrict__ rs, const float* __restrict__ cs,
             float* __restrict__ denom, int rcStride, float scale)
{
  constexpr int NL = 4;   // gld16 per wave per tile

  const int bz = blockIdx.z;
  A += (long long)bz * sA;
  B += (long long)bz * sB;
  if (MODE == 2) { rs += (long long)bz * rcStride; cs += (long long)bz * rcStride;
                   denom += (long long)bz * rcStride; }
  if (MODE == 3) { rs += (long long)bz * rcStride; }
  const int m0 = blockIdx.y * 128, n0 = blockIdx.x * 128;
  const int tid = threadIdx.x;
  const int w = tid >> 6, lane = tid & 63;
  const int wm = (w >> 1) * 64, wn = (w & 1) * 64;
  const int rl = lane & 15, qd = lane >> 4;

  __shared__ __align__(16) unsigned short As[3][128 * 32];
  __shared__ __align__(16) unsigned short Bs[3][128 * 32];

  const int sr = lane >> 2, sg = lane & 3;
  const int ml0 = 32 * w + sr, ml1 = ml0 + 16;
  const int q0 = sg ^ ((ml0 >> 1) & 3), q1 = sg ^ ((ml1 >> 1) & 3);
  const unsigned short* gA0 = A + (long long)(m0 + ml0) * lda + q0 * 8;
  const unsigned short* gA1 = A + (long long)(m0 + ml1) * lda + q1 * 8;
  const unsigned short* gB0 = B + (long long)(n0 + ml0) * ldb + q0 * 8;
  const unsigned short* gB1 = B + (long long)(n0 + ml1) * ldb + q1 * 8;

  int aoff[4], boff[4];
  #pragma unroll
  for (int i = 0; i < 4; ++i) {
    const int mr = wm + i * 16 + rl;
    aoff[i] = mr * 32 + ((qd ^ ((mr >> 1) & 3)) * 8);
    const int nr = wn + i * 16 + rl;
    boff[i] = nr * 32 + ((qd ^ ((nr >> 1) & 3)) * 8);
  }

  floatx4 acc[4][4];
  #pragma unroll
  for (int i = 0; i < 4; ++i)
    #pragma unroll
    for (int j = 0; j < 4; ++j) acc[i][j] = 0.0f;

  auto stage = [&](int t, int bf) {
    const int ko = t * 32;
    gld16(gA0 + ko, As[bf] + (32 * w) * 32);
    gld16(gA1 + ko, As[bf] + (32 * w + 16) * 32);
    gld16(gB0 + ko, Bs[bf] + (32 * w) * 32);
    gld16(gB1 + ko, Bs[bf] + (32 * w + 16) * 32);
  };
  auto compute = [&](int bf) {
    short8 fa[4], fb[4];
    #pragma unroll
    for (int i = 0; i < 4; ++i) fa[i] = *(const short8*)(As[bf] + aoff[i]);
    #pragma unroll
    for (int j = 0; j < 4; ++j) fb[j] = *(const short8*)(Bs[bf] + boff[j]);
    #pragma unroll
    for (int i = 0; i < 4; ++i)
      #pragma unroll
      for (int j = 0; j < 4; ++j)
        acc[i][j] = __builtin_amdgcn_mfma_f32_16x16x32_bf16(fa[i], fb[j], acc[i][j], 0, 0, 0);
  };

  const int niter = K >> 5;
  stage(0, 0);
  stage(1, 1);
  int buf = 0;
  for (int i = 0; i < niter - 1; ++i) {
    asm volatile("s_waitcnt vmcnt(%0)\n\ts_barrier" :: "i"(NL) : "memory");
    if (i + 2 < niter) {
      int nb = buf + 2; if (nb >= 3) nb -= 3;
      stage(i + 2, nb);
    }
    compute(buf);
    if (++buf == 3) buf = 0;
  }
  asm volatile("s_waitcnt vmcnt(0)\n\ts_barrier" ::: "memory");
  compute(buf);

  #pragma unroll
  for (int i = 0; i < 4; ++i) {
    #pragma unroll
    for (int r = 0; r < 4; ++r) {
      const int row = m0 + wm + i * 16 + qd * 4 + r;
      float rowf = 0.f;
      if (MODE == 2) rowf = rs[row] * scale;
      if (MODE == 3) rowf = 1.0f / rs[row];
      float rsum = 0.f;
      #pragma unroll
      for (int j = 0; j < 4; ++j) {
        const int col = n0 + wn + j * 16 + rl;
        float v = acc[i][j][r];
        if (MODE == 2) {
          const float s = v * rowf * cs[col];
          const unsigned short pb = f2b(__expf(s - scale));
          rsum += b2f(pb);
          ((unsigned short*)Cout)[(long long)bz * sC + (long long)row * ldc + col] = pb;
          continue;
        }
        if (MODE == 3) v *= rowf;
        const long long idx = (long long)bz * sC + (long long)row * ldc + col;
        if (OUT_BF16) ((unsigned short*)Cout)[idx] = f2b(v);
        else          ((float*)Cout)[idx] = v;
      }
      if (MODE == 2) {
        #pragma unroll
        for (int m = 1; m < 16; m <<= 1) rsum += __shfl_xor(rsum, m);
        if (rl == 0) atomicAdd(denom + row, rsum);
      }
    }
  }
}

// ---------------------------------------------------------------------------
// gemm_tn1024: 256x256/BK=32 TN bf16 GEMM, 1024 thr = 16 waves (4x4 of
// 64x64). Same proven 3-ring + counted-vmcnt schedule as gemm_tn, but
// 4 waves/SIMD TLP (acc=64 fp32/lane keeps total regs <=128 -> 16 waves/CU).
// LDS = 3 bufs x (A 256x32 + B 256x32) bf16 = 96 KiB (dynamic).
// NL=2 (2 gld16 per thread per K-tile). Fragment swizzle term is
// i-independent ((mr+16i)>>1 & 3 invariant), so frag addrs are 2 base regs
// + immediate ds_read offsets.
// ---------------------------------------------------------------------------
template<bool OUT_BF16, int MODE>
__global__ __launch_bounds__(1024)
void gemm_tn1024(const unsigned short* __restrict__ A, const unsigned short* __restrict__ B,
                 void* __restrict__ Cout, int K, int lda, int ldb, int ldc,
                 long long sA, long long sB, long long sC,
                 const float* __restrict__ rs, const float* __restrict__ cs,
                 float* __restrict__ denom, int rcStride, float scale)
{
  extern __shared__ unsigned short S[];   // [3][A 8192 | B 8192] shorts

  const int bz = blockIdx.z;
  A += (long long)bz * sA;
  B += (long long)bz * sB;
  if (MODE == 2) { rs += (long long)bz * rcStride; cs += (long long)bz * rcStride;
                   denom += (long long)bz * rcStride; }
  if (MODE == 3) { rs += (long long)bz * rcStride; }
  const int m0 = blockIdx.y * 256, n0 = blockIdx.x * 256;
  const int tid = threadIdx.x;
  const int w = tid >> 6, lane = tid & 63;
  const int wm = (w >> 2) * 64, wn = (w & 3) * 64;
  const int rl = lane & 15, qd = lane >> 4;

  // staging: wave w covers rows [16w, 16w+16); lane -> row 16w+(lane>>2),
  // granule slot lane&3; global granule pre-swizzled (slot^((row>>1)&3)).
  const int srow = w * 16 + (lane >> 2), sg = lane & 3;
  const int qa = sg ^ ((srow >> 1) & 3);
  const unsigned short* gA = A + (long long)(m0 + srow) * lda + qa * 8;
  const unsigned short* gB = B + (long long)(n0 + srow) * ldb + qa * 8;

  // fragment read bases (swizzle-corrected; i-step = +512 elems)
  const int ar = wm + rl, br = wn + rl;
  const int aoff0 = ar * 32 + ((qd ^ ((ar >> 1) & 3)) * 8);
  const int boff0 = br * 32 + ((qd ^ ((br >> 1) & 3)) * 8);

  floatx4 acc[4][4];
  #pragma unroll
  for (int i = 0; i < 4; ++i)
    #pragma unroll
    for (int j = 0; j < 4; ++j) acc[i][j] = 0.0f;

  auto stage = [&](int t, int bf) {
    const int ko = t * 32;
    gld16(gA + ko, S + bf * 16384 + w * 512);
    gld16(gB + ko, S + bf * 16384 + 8192 + w * 512);
  };
  auto compute = [&](int bf) {
    short8 fa[4], fb[4];
    const unsigned short* pA = S + bf * 16384 + aoff0;
    const unsigned short* pB = S + bf * 16384 + 8192 + boff0;
    #pragma unroll
    for (int i = 0; i < 4; ++i) fa[i] = *(const short8*)(pA + i * 512);
    #pragma unroll
    for (int j = 0; j < 4; ++j) fb[j] = *(const short8*)(pB + j * 512);
    #pragma unroll
    for (int i = 0; i < 4; ++i)
      #pragma unroll
      for (int j = 0; j < 4; ++j)
        acc[i][j] = __builtin_amdgcn_mfma_f32_16x16x32_bf16(fa[i], fb[j], acc[i][j], 0, 0, 0);
  };

  const int niter = K >> 5;
  stage(0, 0);
  stage(1, 1);
  int buf = 0;
  for (int i = 0; i < niter - 1; ++i) {
    asm volatile("s_waitcnt vmcnt(2)\n\ts_barrier" ::: "memory");
    if (i + 2 < niter) {
      int nb = buf + 2; if (nb >= 3) nb -= 3;
      stage(i + 2, nb);
    }
    compute(buf);
    if (++buf == 3) buf = 0;
  }
  asm volatile("s_waitcnt vmcnt(0)\n\ts_barrier" ::: "memory");
  compute(buf);

  // epilogue: C/D layout col=lane&15, row=(lane>>4)*4+reg
  #pragma unroll
  for (int i = 0; i < 4; ++i) {
    #pragma unroll
    for (int r = 0; r < 4; ++r) {
      const int row = m0 + wm + i * 16 + qd * 4 + r;
      float rowf = 0.f;
      if (MODE == 2) rowf = rs[row] * scale;
      if (MODE == 3) rowf = 1.0f / rs[row];
      float rsum = 0.f;
      #pragma unroll
      for (int j = 0; j < 4; ++j) {
        const int col = n0 + wn + j * 16 + rl;
        float v = acc[i][j][r];
        if (MODE == 2) {
          const float s = v * rowf * cs[col];
          const unsigned short pb = f2b(__expf(s - scale));
          rsum += b2f(pb);   // sum the ROUNDED weights
          ((unsigned short*)Cout)[(long long)bz * sC + (long long)row * ldc + col] = pb;
          continue;
        }
        if (MODE == 3) v *= rowf;
        const long long idx = (long long)bz * sC + (long long)row * ldc + col;
        if (OUT_BF16) ((unsigned short*)Cout)[idx] = f2b(v);
        else          ((float*)Cout)[idx] = v;
      }
      if (MODE == 2) {
        #pragma unroll
        for (int m = 1; m < 16; m <<= 1) rsum += __shfl_xor(rsum, m);
        if (rl == 0) atomicAdd(denom + row, rsum);
      }
    }
  }
}

__global__ __launch_bounds__(256)
void zero_f(float* __restrict__ p, int n)
{
  const int i = blockIdx.x * 256 + threadIdx.x;
  if (i < n) p[i] = 0.f;
}

__global__ __launch_bounds__(256)
void fin_inv(float* __restrict__ p, int n)
{
  const int i = blockIdx.x * 256 + threadIdx.x;
  if (i < n) p[i] = 1.f / fmaxf(sqrtf(p[i]), 1e-12f);
}

__global__ __launch_bounds__(256)
void conv_xT(const float* __restrict__ x, unsigned short* __restrict__ xT)
{
  const int b = blockIdx.z, t0 = blockIdx.x * 32, c0 = blockIdx.y * 32;
  const int tx = threadIdx.x & 31, ty = threadIdx.x >> 5;
  __shared__ float tile[32][33];
  const float* src = x + (long long)b * C_ * T_;
  #pragma unroll
  for (int r = 0; r < 4; ++r)
    tile[ty + 8 * r][tx] = src[(long long)(c0 + ty + 8 * r) * T_ + t0 + tx];
  __syncthreads();
  unsigned short* dst = xT + (long long)b * T_ * C_;
  #pragma unroll
  for (int r = 0; r < 4; ++r)
    dst[(long long)(t0 + ty + 8 * r) * C_ + c0 + tx] = f2b(tile[tx][ty + 8 * r]);
}

__global__ __launch_bounds__(256)
void conv_bf(const float* __restrict__ in, unsigned short* __restrict__ out, int n)
{
  const int i = blockIdx.x * 256 + threadIdx.x;
  if (i < n) out[i] = f2b(in[i]);
}

// ---------------------------------------------------------------------------
// Fused depthwise-3 for q/k/v (p = blockIdx.z%3): 32x32 tiles of [B,3C,T].
//  p<2 : conv + transpose -> qT/kT [B,T,C] bf16, plus channel sum-of-squares
//        of the ROUNDED bf16 values, reduced per 32-lane group and atomically
//        accumulated into sq_q/sq_k (later finalized in-place by fin_inv).
//  p==2: conv -> vb [B,C,T] bf16 (no transpose).
// Replaces dw_qk_t + dw_v + norms_k (removes the 32 MB norms re-read).
// ---------------------------------------------------------------------------
__global__ __launch_bounds__(256)
void dw_qkv_t(const unsigned short* __restrict__ qkv, const float* __restrict__ wdw,
              unsigned short* __restrict__ qT, unsigned short* __restrict__ kT,
              unsigned short* __restrict__ vout,
              float* __restrict__ sq_q, float* __restrict__ sq_k)
{
  const int bz = blockIdx.z, b = bz / 3, p = bz % 3;
  const int t0 = blockIdx.x * 32, c0 = blockIdx.y * 32;
  const int tx = threadIdx.x & 31, ty = threadIdx.x >> 5;
  __shared__ float tin[32][34];   // [c][t-1 .. t+32]
  __shared__ float tout[32][33];  // [t][c]
  const int chb = b * C3_ + p * C_;
  #pragma unroll
  for (int r = 0; r < 4; ++r) {
    const int cy = ty + 8 * r;
    const unsigned short* src = qkv + (long long)(chb + c0 + cy) * T_;
    int t = t0 - 1 + tx;
    tin[cy][tx] = (t >= 0 && t < T_) ? b2f(src[t]) : 0.f;
    if (tx < 2) {
      const int t2 = t0 + 31 + tx;
      tin[cy][32 + tx] = (t2 < T_) ? b2f(src[t2]) : 0.f;
    }
  }
  __syncthreads();
  if (p == 2) {
    #pragma unroll
    for (int r = 0; r < 4; ++r) {
      const int cy = ty + 8 * r;
      const float* wp = wdw + (2 * C_ + c0 + cy) * 3;
      const float v = fmaf(wp[0], tin[cy][tx], fmaf(wp[1], tin[cy][tx + 1], wp[2] * tin[cy][tx + 2]));
      vout[(long long)(b * C_ + c0 + cy) * T_ + t0 + tx] = f2b(v);
    }
    return;
  }
  #pragma unroll
  for (int r = 0; r < 4; ++r) {
    const int cy = ty + 8 * r;
    const float* wp = wdw + (p * C_ + c0 + cy) * 3;
    tout[tx][cy] = fmaf(wp[0], tin[cy][tx], fmaf(wp[1], tin[cy][tx + 1], wp[2] * tin[cy][tx + 2]));
  }
  __syncthreads();
  unsigned short* dst = (p == 0 ? qT : kT) + (long long)b * T_ * C_;
  float* sq = (p == 0 ? sq_q : sq_k) + (long long)b * T_;
  #pragma unroll
  for (int r = 0; r < 4; ++r) {
    const int tl = ty + 8 * r;
    const unsigned short ub = f2b(tout[tl][tx]);
    dst[(long long)(t0 + tl) * C_ + c0 + tx] = ub;
    const float fv = b2f(ub);
    float ssq = fv * fv;
    #pragma unroll
    for (int m = 1; m < 32; m <<= 1) ssq += __shfl_xor(ssq, m);
    if (tx == 0) atomicAdd(sq + t0 + tl, ssq);
  }
}

// ---------------------------------------------------------------------------
// Workspace arena (bytes), ~185.3 MB — same layout as round 0.
//  inv_nq/inv_nk double as the sum-of-squares accumulators (zeroed, atomics,
//  then fin_inv transforms in place). inv_nq, inv_nk, denom are contiguous.
// ---------------------------------------------------------------------------
extern "C" void kernel_launch(void* const* d_in, const int* in_sizes, int n_in,
                              void* d_out, int out_size, void* d_ws, size_t ws_size,
                              hipStream_t stream)
{
  const float* x      = (const float*)d_in[0];
  const float* w_qkv  = (const float*)d_in[1];
  const float* w_dw   = (const float*)d_in[2];
  const float* w_proj = (const float*)d_in[3];
  float* out = (float*)d_out;

  static int attr_done = 0;
  if (!attr_done) {
    hipFuncSetAttribute((const void*)&gemm_tn1024<true, 2>,
                        hipFuncAttributeMaxDynamicSharedMemorySize, 98304);
    attr_done = 1;
  }

  char* base = (char*)d_ws;
  unsigned short* xT      = (unsigned short*)base;                    // early
  unsigned short* wqkv_bf = (unsigned short*)(base + 16777216);       // early
  unsigned short* av_t    = (unsigned short*)base;                    // late
  char* p = base + 67108864;
  unsigned short* qT = (unsigned short*)p; p += 16777216;
  unsigned short* kT = (unsigned short*)p; p += 16777216;
  unsigned short* vb = (unsigned short*)p; p += 16777216;
  unsigned short* attn   = (unsigned short*)p;
  unsigned short* qkv_bf = (unsigned short*)p;                        // early alias
  p += 67108864;
  unsigned short* wproj_bf = (unsigned short*)p; p += 524288;
  float* inv_nq = (float*)p; p += 65536;
  float* inv_nk = (float*)p; p += 65536;
  float* denom  = (float*)p;

  const long long TC = (long long)T_ * C_, TT = (long long)T_ * T_;

  // 0) conversions + zero (inv_nq | inv_nk | denom contiguous = 3*B*T floats)
  conv_xT<<<dim3(T_ / 32, C_ / 32, B_), 256, 0, stream>>>(x, xT);
  conv_bf<<<(C3_ * C_) / 256, 256, 0, stream>>>(w_qkv, wqkv_bf, C3_ * C_);
  conv_bf<<<(C_ * C_) / 256, 256, 0, stream>>>(w_proj, wproj_bf, C_ * C_);
  zero_f<<<(3 * B_ * T_) / 256, 256, 0, stream>>>(inv_nq, 3 * B_ * T_);

  // 1) qkv: 128^2 kernel, grid 1536 blocks (full GPU)
  gemm_tn<true, 0><<<dim3(16, 12, B_), 256, 0, stream>>>(
      wqkv_bf, xT, qkv_bf, C_, C_, C_, T_,
      0LL, TC, (long long)C3_ * T_, nullptr, nullptr, nullptr, 0, 1.f);

  // 2) fused depthwise conv (q,k transposed + norm partials; v plain)
  dw_qkv_t<<<dim3(T_ / 32, C_ / 32, B_ * 3), 256, 0, stream>>>(
      qkv_bf, w_dw, qT, kT, vb, inv_nq, inv_nk);
  fin_inv<<<(2 * B_ * T_) / 256, 256, 0, stream>>>(inv_nq, 2 * B_ * T_);

  // 3) attn: 256^2 16-wave 3-ring kernel, grid 512 = 2 clean rounds
  gemm_tn1024<true, 2><<<dim3(8, 8, B_), 1024, 98304, stream>>>(
      qT, kT, attn, C_, C_, C_, T_,
      TC, TC, TT, inv_nq, inv_nk, denom, T_, INV_TEMP);

  // 4) AV: 128^2 kernel, grid 512 blocks (full GPU)
  gemm_tn<true, 3><<<dim3(4, 16, B_), 256, 0, stream>>>(
      attn, vb, av_t, T_, T_, T_, C_,
      TT, (long long)C_ * T_, TC, denom, nullptr, nullptr, T_, 1.f);

  // 5) proj: 128^2 kernel, grid 512 blocks
  gemm_tn<false, 0><<<dim3(16, 4, B_), 256, 0, stream>>>(
      wproj_bf, av_t, out, C_, C_, C_, T_,
      0LL, TC, (long long)C_ * T_, nullptr, nullptr, nullptr, 0, 1.f);
}

// Round 6
// 286.314 us; speedup vs baseline: 1.1618x; 1.1618x over previous
//
#include <hip/hip_runtime.h>
#include <math.h>

static constexpr int B_ = 8, C_ = 512, T_ = 2048, C3_ = 1536;
static constexpr float INV_TEMP = 1.0f / 0.07f;

typedef __attribute__((ext_vector_type(8))) short short8;
typedef __attribute__((ext_vector_type(4))) float floatx4;

__device__ __forceinline__ float b2f(unsigned short u) {
  union { unsigned int i; float f; } v; v.i = ((unsigned int)u) << 16; return v.f;
}
__device__ __forceinline__ unsigned short f2b(float f) {
  union { float f; unsigned int i; } v; v.f = f;
  const unsigned int x = v.i;
  return (unsigned short)((x + 0x7FFFu + ((x >> 16) & 1u)) >> 16);
}
__device__ __forceinline__ void gld16(const unsigned short* g, unsigned short* l) {
  __builtin_amdgcn_global_load_lds(
      (const __attribute__((address_space(1))) void*)g,
      (__attribute__((address_space(3))) void*)l, 16, 0, 0);
}

// ---------------------------------------------------------------------------
// gemm_tn: proven 128x128/BK=32 TN bf16 GEMM (3-deep LDS ring, counted
// vmcnt(4) at the barrier). Used for qkv / AV / proj.
// MODE 0: plain store. MODE 2: softmax epilogue. MODE 3: row divide.
// ---------------------------------------------------------------------------
template<bool OUT_BF16, int MODE>
__global__ __launch_bounds__(256)
void gemm_tn(const unsigned short* __restrict__ A, const unsigned short* __restrict__ B,
             void* __restrict__ Cout, int K, int lda, int ldb, int ldc,
             long long sA, long long sB, long long sC,
             const float* __restrict__ rs, const float* __restrict__ cs,
             float* __restrict__ denom, int rcStride, float scale)
{
  constexpr int NL = 4;   // gld16 per wave per tile

  const int bz = blockIdx.z;
  A += (long long)bz * sA;
  B += (long long)bz * sB;
  if (MODE == 2) { rs += (long long)bz * rcStride; cs += (long long)bz * rcStride;
                   denom += (long long)bz * rcStride; }
  if (MODE == 3) { rs += (long long)bz * rcStride; }
  const int m0 = blockIdx.y * 128, n0 = blockIdx.x * 128;
  const int tid = threadIdx.x;
  const int w = tid >> 6, lane = tid & 63;
  const int wm = (w >> 1) * 64, wn = (w & 1) * 64;
  const int rl = lane & 15, qd = lane >> 4;

  __shared__ __align__(16) unsigned short As[3][128 * 32];
  __shared__ __align__(16) unsigned short Bs[3][128 * 32];

  const int sr = lane >> 2, sg = lane & 3;
  const int ml0 = 32 * w + sr, ml1 = ml0 + 16;
  const int q0 = sg ^ ((ml0 >> 1) & 3), q1 = sg ^ ((ml1 >> 1) & 3);
  const unsigned short* gA0 = A + (long long)(m0 + ml0) * lda + q0 * 8;
  const unsigned short* gA1 = A + (long long)(m0 + ml1) * lda + q1 * 8;
  const unsigned short* gB0 = B + (long long)(n0 + ml0) * ldb + q0 * 8;
  const unsigned short* gB1 = B + (long long)(n0 + ml1) * ldb + q1 * 8;

  int aoff[4], boff[4];
  #pragma unroll
  for (int i = 0; i < 4; ++i) {
    const int mr = wm + i * 16 + rl;
    aoff[i] = mr * 32 + ((qd ^ ((mr >> 1) & 3)) * 8);
    const int nr = wn + i * 16 + rl;
    boff[i] = nr * 32 + ((qd ^ ((nr >> 1) & 3)) * 8);
  }

  floatx4 acc[4][4];
  #pragma unroll
  for (int i = 0; i < 4; ++i)
    #pragma unroll
    for (int j = 0; j < 4; ++j) acc[i][j] = 0.0f;

  auto stage = [&](int t, int bf) {
    const int ko = t * 32;
    gld16(gA0 + ko, As[bf] + (32 * w) * 32);
    gld16(gA1 + ko, As[bf] + (32 * w + 16) * 32);
    gld16(gB0 + ko, Bs[bf] + (32 * w) * 32);
    gld16(gB1 + ko, Bs[bf] + (32 * w + 16) * 32);
  };
  auto compute = [&](int bf) {
    short8 fa[4], fb[4];
    #pragma unroll
    for (int i = 0; i < 4; ++i) fa[i] = *(const short8*)(As[bf] + aoff[i]);
    #pragma unroll
    for (int j = 0; j < 4; ++j) fb[j] = *(const short8*)(Bs[bf] + boff[j]);
    #pragma unroll
    for (int i = 0; i < 4; ++i)
      #pragma unroll
      for (int j = 0; j < 4; ++j)
        acc[i][j] = __builtin_amdgcn_mfma_f32_16x16x32_bf16(fa[i], fb[j], acc[i][j], 0, 0, 0);
  };

  const int niter = K >> 5;
  stage(0, 0);
  stage(1, 1);
  int buf = 0;
  for (int i = 0; i < niter - 1; ++i) {
    asm volatile("s_waitcnt vmcnt(%0)\n\ts_barrier" :: "i"(NL) : "memory");
    if (i + 2 < niter) {
      int nb = buf + 2; if (nb >= 3) nb -= 3;
      stage(i + 2, nb);
    }
    compute(buf);
    if (++buf == 3) buf = 0;
  }
  asm volatile("s_waitcnt vmcnt(0)\n\ts_barrier" ::: "memory");
  compute(buf);

  #pragma unroll
  for (int i = 0; i < 4; ++i) {
    #pragma unroll
    for (int r = 0; r < 4; ++r) {
      const int row = m0 + wm + i * 16 + qd * 4 + r;
      float rowf = 0.f;
      if (MODE == 2) rowf = rs[row] * scale;
      if (MODE == 3) rowf = 1.0f / rs[row];
      float rsum = 0.f;
      #pragma unroll
      for (int j = 0; j < 4; ++j) {
        const int col = n0 + wn + j * 16 + rl;
        float v = acc[i][j][r];
        if (MODE == 2) {
          const float s = v * rowf * cs[col];
          const unsigned short pb = f2b(__expf(s - scale));
          rsum += b2f(pb);
          ((unsigned short*)Cout)[(long long)bz * sC + (long long)row * ldc + col] = pb;
          continue;
        }
        if (MODE == 3) v *= rowf;
        const long long idx = (long long)bz * sC + (long long)row * ldc + col;
        if (OUT_BF16) ((unsigned short*)Cout)[idx] = f2b(v);
        else          ((float*)Cout)[idx] = v;
      }
      if (MODE == 2) {
        #pragma unroll
        for (int m = 1; m < 16; m <<= 1) rsum += __shfl_xor(rsum, m);
        if (rl == 0) atomicAdd(denom + row, rsum);
      }
    }
  }
}

// ---------------------------------------------------------------------------
// gemm_tn1024: 256x256/BK=32 TN bf16 GEMM, 1024 thr = 16 waves (4x4 of
// 64x64). Same proven 3-ring + counted-vmcnt schedule as gemm_tn, but
// 4 waves/SIMD TLP. LDS = 3 x 32 KiB (dynamic). NL=2.
// ---------------------------------------------------------------------------
template<bool OUT_BF16, int MODE>
__global__ __launch_bounds__(1024)
void gemm_tn1024(const unsigned short* __restrict__ A, const unsigned short* __restrict__ B,
                 void* __restrict__ Cout, int K, int lda, int ldb, int ldc,
                 long long sA, long long sB, long long sC,
                 const float* __restrict__ rs, const float* __restrict__ cs,
                 float* __restrict__ denom, int rcStride, float scale)
{
  extern __shared__ unsigned short S[];   // [3][A 8192 | B 8192] shorts

  const int bz = blockIdx.z;
  A += (long long)bz * sA;
  B += (long long)bz * sB;
  if (MODE == 2) { rs += (long long)bz * rcStride; cs += (long long)bz * rcStride;
                   denom += (long long)bz * rcStride; }
  if (MODE == 3) { rs += (long long)bz * rcStride; }
  const int m0 = blockIdx.y * 256, n0 = blockIdx.x * 256;
  const int tid = threadIdx.x;
  const int w = tid >> 6, lane = tid & 63;
  const int wm = (w >> 2) * 64, wn = (w & 3) * 64;
  const int rl = lane & 15, qd = lane >> 4;

  const int srow = w * 16 + (lane >> 2), sg = lane & 3;
  const int qa = sg ^ ((srow >> 1) & 3);
  const unsigned short* gA = A + (long long)(m0 + srow) * lda + qa * 8;
  const unsigned short* gB = B + (long long)(n0 + srow) * ldb + qa * 8;

  const int ar = wm + rl, br = wn + rl;
  const int aoff0 = ar * 32 + ((qd ^ ((ar >> 1) & 3)) * 8);
  const int boff0 = br * 32 + ((qd ^ ((br >> 1) & 3)) * 8);

  floatx4 acc[4][4];
  #pragma unroll
  for (int i = 0; i < 4; ++i)
    #pragma unroll
    for (int j = 0; j < 4; ++j) acc[i][j] = 0.0f;

  auto stage = [&](int t, int bf) {
    const int ko = t * 32;
    gld16(gA + ko, S + bf * 16384 + w * 512);
    gld16(gB + ko, S + bf * 16384 + 8192 + w * 512);
  };
  auto compute = [&](int bf) {
    short8 fa[4], fb[4];
    const unsigned short* pA = S + bf * 16384 + aoff0;
    const unsigned short* pB = S + bf * 16384 + 8192 + boff0;
    #pragma unroll
    for (int i = 0; i < 4; ++i) fa[i] = *(const short8*)(pA + i * 512);
    #pragma unroll
    for (int j = 0; j < 4; ++j) fb[j] = *(const short8*)(pB + j * 512);
    #pragma unroll
    for (int i = 0; i < 4; ++i)
      #pragma unroll
      for (int j = 0; j < 4; ++j)
        acc[i][j] = __builtin_amdgcn_mfma_f32_16x16x32_bf16(fa[i], fb[j], acc[i][j], 0, 0, 0);
  };

  const int niter = K >> 5;
  stage(0, 0);
  stage(1, 1);
  int buf = 0;
  for (int i = 0; i < niter - 1; ++i) {
    asm volatile("s_waitcnt vmcnt(2)\n\ts_barrier" ::: "memory");
    if (i + 2 < niter) {
      int nb = buf + 2; if (nb >= 3) nb -= 3;
      stage(i + 2, nb);
    }
    compute(buf);
    if (++buf == 3) buf = 0;
  }
  asm volatile("s_waitcnt vmcnt(0)\n\ts_barrier" ::: "memory");
  compute(buf);

  #pragma unroll
  for (int i = 0; i < 4; ++i) {
    #pragma unroll
    for (int r = 0; r < 4; ++r) {
      const int row = m0 + wm + i * 16 + qd * 4 + r;
      float rowf = 0.f;
      if (MODE == 2) rowf = rs[row] * scale;
      if (MODE == 3) rowf = 1.0f / rs[row];
      float rsum = 0.f;
      #pragma unroll
      for (int j = 0; j < 4; ++j) {
        const int col = n0 + wn + j * 16 + rl;
        float v = acc[i][j][r];
        if (MODE == 2) {
          const float s = v * rowf * cs[col];
          const unsigned short pb = f2b(__expf(s - scale));
          rsum += b2f(pb);
          ((unsigned short*)Cout)[(long long)bz * sC + (long long)row * ldc + col] = pb;
          continue;
        }
        if (MODE == 3) v *= rowf;
        const long long idx = (long long)bz * sC + (long long)row * ldc + col;
        if (OUT_BF16) ((unsigned short*)Cout)[idx] = f2b(v);
        else          ((float*)Cout)[idx] = v;
      }
      if (MODE == 2) {
        #pragma unroll
        for (int m = 1; m < 16; m <<= 1) rsum += __shfl_xor(rsum, m);
        if (rl == 0) atomicAdd(denom + row, rsum);
      }
    }
  }
}

__global__ __launch_bounds__(256)
void zero_f(float* __restrict__ p, int n)
{
  const int i = blockIdx.x * 256 + threadIdx.x;
  if (i < n) p[i] = 0.f;
}

__global__ __launch_bounds__(256)
void fin_inv(float* __restrict__ p, int n)
{
  const int i = blockIdx.x * 256 + threadIdx.x;
  if (i < n) p[i] = 1.f / fmaxf(sqrtf(p[i]), 1e-12f);
}

__global__ __launch_bounds__(256)
void conv_xT(const float* __restrict__ x, unsigned short* __restrict__ xT)
{
  const int b = blockIdx.z, t0 = blockIdx.x * 32, c0 = blockIdx.y * 32;
  const int tx = threadIdx.x & 31, ty = threadIdx.x >> 5;
  __shared__ float tile[32][33];
  const float* src = x + (long long)b * C_ * T_;
  #pragma unroll
  for (int r = 0; r < 4; ++r)
    tile[ty + 8 * r][tx] = src[(long long)(c0 + ty + 8 * r) * T_ + t0 + tx];
  __syncthreads();
  unsigned short* dst = xT + (long long)b * T_ * C_;
  #pragma unroll
  for (int r = 0; r < 4; ++r)
    dst[(long long)(t0 + ty + 8 * r) * C_ + c0 + tx] = f2b(tile[tx][ty + 8 * r]);
}

__global__ __launch_bounds__(256)
void conv_bf(const float* __restrict__ in, unsigned short* __restrict__ out, int n)
{
  const int i = blockIdx.x * 256 + threadIdx.x;
  if (i < n) out[i] = f2b(in[i]);
}

// ---------------------------------------------------------------------------
// dw_qkv_v2: fully-vectorized depthwise-3 for q/k/v (p = blockIdx.z%3) on
// 64t x 64c tiles of [B,3C,T] bf16.
//  staging: short8 16B loads (128B-aligned rows, no over-fetch) into
//           tin[64][80] (cols 8..71 = t0..t0+63; col 7 = t0-1; col 72 = t0+64,
//           2 scalar edge loads per row).
//  p<2 : conv in registers -> f32 tout[64][65] ([t][c], 65-stride = 2-way
//        banks = free) -> vectorized short8 stores to qT/kT [B,T,C], plus
//        channel sum-of-squares of the ROUNDED bf16 (8-lane shuffle reduce,
//        1 atomic per row) into sq_q/sq_k (finalized by fin_inv).
//  p==2: conv -> 2x short8 stores per thread to vb [B,C,T] (no transpose).
// Replaces r5's scalar dw_qkv_t (81 us, 1.9 TB/s, 2x read over-fetch).
// ---------------------------------------------------------------------------
__global__ __launch_bounds__(256)
void dw_qkv_v2(const unsigned short* __restrict__ qkv, const float* __restrict__ wdw,
               unsigned short* __restrict__ qT, unsigned short* __restrict__ kT,
               unsigned short* __restrict__ vout,
               float* __restrict__ sq_q, float* __restrict__ sq_k)
{
  const int bz = blockIdx.z, b = bz / 3, p = bz % 3;
  const int t0 = blockIdx.x * 64, c0 = blockIdx.y * 64;
  const int tid = threadIdx.x;
  __shared__ unsigned short tin[64][80];
  __shared__ float tout[64][65];
  const int chb = b * C3_ + p * C_;

  #pragma unroll
  for (int s = 0; s < 2; ++s) {
    const int idx = tid + s * 256;
    const int cy = idx >> 3, g = idx & 7;
    *(short8*)&tin[cy][8 + 8 * g] =
        *(const short8*)(qkv + (long long)(chb + c0 + cy) * T_ + t0 + 8 * g);
  }
  if (tid < 64) {
    tin[tid][7] = (t0 > 0) ? qkv[(long long)(chb + c0 + tid) * T_ + t0 - 1]
                           : (unsigned short)0;
  } else if (tid < 128) {
    const int cy = tid - 64;
    tin[cy][72] = (t0 + 64 < T_) ? qkv[(long long)(chb + c0 + cy) * T_ + t0 + 64]
                                 : (unsigned short)0;
  }
  __syncthreads();

  const int cy = tid >> 2, tg = tid & 3;
  const float* wp = wdw + (p * C_ + c0 + cy) * 3;
  const float w0 = wp[0], w1 = wp[1], w2 = wp[2];

  if (p == 2) {
    short8 o0, o1;
    #pragma unroll
    for (int i = 0; i < 16; ++i) {
      const int j = 16 * tg + i;
      const float v = fmaf(w0, b2f(tin[cy][7 + j]),
                      fmaf(w1, b2f(tin[cy][8 + j]), w2 * b2f(tin[cy][9 + j])));
      if (i < 8) o0[i] = (short)f2b(v); else o1[i - 8] = (short)f2b(v);
    }
    unsigned short* d = vout + (long long)(b * C_ + c0 + cy) * T_ + t0 + 16 * tg;
    *(short8*)d = o0;
    *(short8*)(d + 8) = o1;
    return;
  }

  #pragma unroll
  for (int i = 0; i < 16; ++i) {
    const int j = 16 * tg + i;
    tout[j][cy] = fmaf(w0, b2f(tin[cy][7 + j]),
                  fmaf(w1, b2f(tin[cy][8 + j]), w2 * b2f(tin[cy][9 + j])));
  }
  __syncthreads();

  unsigned short* dst = (p == 0 ? qT : kT) + (long long)b * T_ * C_;
  float* sq = (p == 0 ? sq_q : sq_k) + (long long)b * T_;
  #pragma unroll
  for (int s = 0; s < 2; ++s) {
    const int idx = tid + s * 256;
    const int tl = idx >> 3, cl = idx & 7;
    short8 o;
    float ssq = 0.f;
    #pragma unroll
    for (int i = 0; i < 8; ++i) {
      const unsigned short ub = f2b(tout[tl][8 * cl + i]);
      o[i] = (short)ub;
      const float fv = b2f(ub);
      ssq = fmaf(fv, fv, ssq);
    }
    *(short8*)(dst + (long long)(t0 + tl) * C_ + c0 + 8 * cl) = o;
    #pragma unroll
    for (int m = 1; m < 8; m <<= 1) ssq += __shfl_xor(ssq, m);
    if (cl == 0) atomicAdd(sq + t0 + tl, ssq);
  }
}

// ---------------------------------------------------------------------------
// Workspace arena (bytes), ~185.3 MB — same layout as round 0.
//  inv_nq/inv_nk double as the sum-of-squares accumulators (zeroed, atomics,
//  then fin_inv transforms in place). inv_nq, inv_nk, denom are contiguous.
// ---------------------------------------------------------------------------
extern "C" void kernel_launch(void* const* d_in, const int* in_sizes, int n_in,
                              void* d_out, int out_size, void* d_ws, size_t ws_size,
                              hipStream_t stream)
{
  const float* x      = (const float*)d_in[0];
  const float* w_qkv  = (const float*)d_in[1];
  const float* w_dw   = (const float*)d_in[2];
  const float* w_proj = (const float*)d_in[3];
  float* out = (float*)d_out;

  static int attr_done = 0;
  if (!attr_done) {
    hipFuncSetAttribute((const void*)&gemm_tn1024<true, 2>,
                        hipFuncAttributeMaxDynamicSharedMemorySize, 98304);
    attr_done = 1;
  }

  char* base = (char*)d_ws;
  unsigned short* xT      = (unsigned short*)base;                    // early
  unsigned short* wqkv_bf = (unsigned short*)(base + 16777216);       // early
  unsigned short* av_t    = (unsigned short*)base;                    // late
  char* p = base + 67108864;
  unsigned short* qT = (unsigned short*)p; p += 16777216;
  unsigned short* kT = (unsigned short*)p; p += 16777216;
  unsigned short* vb = (unsigned short*)p; p += 16777216;
  unsigned short* attn   = (unsigned short*)p;
  unsigned short* qkv_bf = (unsigned short*)p;                        // early alias
  p += 67108864;
  unsigned short* wproj_bf = (unsigned short*)p; p += 524288;
  float* inv_nq = (float*)p; p += 65536;
  float* inv_nk = (float*)p; p += 65536;
  float* denom  = (float*)p;

  const long long TC = (long long)T_ * C_, TT = (long long)T_ * T_;

  // 0) conversions + zero (inv_nq | inv_nk | denom contiguous = 3*B*T floats)
  conv_xT<<<dim3(T_ / 32, C_ / 32, B_), 256, 0, stream>>>(x, xT);
  conv_bf<<<(C3_ * C_) / 256, 256, 0, stream>>>(w_qkv, wqkv_bf, C3_ * C_);
  conv_bf<<<(C_ * C_) / 256, 256, 0, stream>>>(w_proj, wproj_bf, C_ * C_);
  zero_f<<<(3 * B_ * T_) / 256, 256, 0, stream>>>(inv_nq, 3 * B_ * T_);

  // 1) qkv: 128^2 kernel, grid 1536 blocks (full GPU)
  gemm_tn<true, 0><<<dim3(16, 12, B_), 256, 0, stream>>>(
      wqkv_bf, xT, qkv_bf, C_, C_, C_, T_,
      0LL, TC, (long long)C3_ * T_, nullptr, nullptr, nullptr, 0, 1.f);

  // 2) fused vectorized depthwise conv (q,k transposed + norm partials; v plain)
  dw_qkv_v2<<<dim3(T_ / 64, C_ / 64, B_ * 3), 256, 0, stream>>>(
      qkv_bf, w_dw, qT, kT, vb, inv_nq, inv_nk);
  fin_inv<<<(2 * B_ * T_) / 256, 256, 0, stream>>>(inv_nq, 2 * B_ * T_);

  // 3) attn: 256^2 16-wave 3-ring kernel, grid 512 = 2 clean rounds
  gemm_tn1024<true, 2><<<dim3(8, 8, B_), 1024, 98304, stream>>>(
      qT, kT, attn, C_, C_, C_, T_,
      TC, TC, TT, inv_nq, inv_nk, denom, T_, INV_TEMP);

  // 4) AV: 128^2 kernel, grid 512 blocks (full GPU)
  gemm_tn<true, 3><<<dim3(4, 16, B_), 256, 0, stream>>>(
      attn, vb, av_t, T_, T_, T_, C_,
      TT, (long long)C_ * T_, TC, denom, nullptr, nullptr, T_, 1.f);

  // 5) proj: 128^2 kernel, grid 512 blocks
  gemm_tn<false, 0><<<dim3(16, 4, B_), 256, 0, stream>>>(
      wproj_bf, av_t, out, C_, C_, C_, T_,
      0LL, TC, (long long)C_ * T_, nullptr, nullptr, nullptr, 0, 1.f);
}